// Round 3
// baseline (737.141 us; speedup 1.0000x reference)
//
#include <hip/hip_runtime.h>

typedef unsigned int u32;
typedef unsigned short u16;
typedef __attribute__((ext_vector_type(8))) short short8;   // 8 bf16 (4 VGPRs)
typedef __attribute__((ext_vector_type(4))) float f32x4;

#define DEV __device__ __forceinline__
#define LOG2E 1.44269504089f

DEV u16 f2bf(float f) {
    u32 u = __float_as_uint(f);
    return (u16)((u + 0x7FFFu + ((u >> 16) & 1u)) >> 16);
}
DEV float bf2f(u16 h) { return __uint_as_float(((u32)h) << 16); }
DEV float frcp(float x) { return __builtin_amdgcn_rcpf(x); }
DEV float fexp2(float x) {
#if __has_builtin(__builtin_amdgcn_exp2f)
    return __builtin_amdgcn_exp2f(x);
#else
    return exp2f(x);
#endif
}
DEV u32 pack_bf16(float a, float b) {
#if __has_builtin(__builtin_amdgcn_cvt_pk_bf16_f32)
    auto v = __builtin_amdgcn_cvt_pk_bf16_f32(a, b);   // lo=a, hi=b
    u32 r; __builtin_memcpy(&r, &v, 4); return r;
#else
    return (u32)f2bf(a) | ((u32)f2bf(b) << 16);
#endif
}
// extract r-th bf16 (r constant under unroll) from packed uint2
DEV float xex(uint2 v, int r) {
    u32 u = (r & 2) ? v.y : v.x;
    return (r & 1) ? __uint_as_float(u & 0xFFFF0000u) : __uint_as_float(u << 16);
}

// ---------------------------------------------------------------------------
// K1: fused embedding gather + input projection, MFMA, both dirs.
// grid = 512: blockIdx = dir*256 + g4*64 + schunk.  Output X is PRE-SCALED by
// log2e so k_lstm's sigmoids/tanh use raw v_exp (base-2) with no arg mul.
// ---------------------------------------------------------------------------
__global__ __launch_bounds__(512) void k_inproj2(
    const int* __restrict__ sent, const float* __restrict__ emb,
    const float* __restrict__ wihf, const float* __restrict__ bihf, const float* __restrict__ bhhf,
    const float* __restrict__ wihb, const float* __restrict__ bihb, const float* __restrict__ bhhb,
    u16* __restrict__ Xf, u16* __restrict__ Xb)
{
    int blk = blockIdx.x;
    int d  = blk >> 8;
    int g4 = (blk >> 6) & 3;
    int sc = blk & 63;
    const float* wih = d ? wihb : wihf;
    const float* bih = d ? bihb : bihf;
    const float* bhh = d ? bhhb : bhhf;
    u16* X = d ? Xb : Xf;
    int tid = threadIdx.x;
    int w = tid >> 6, lane = tid & 63;
    int rg = lane >> 4, cn = lane & 15;

    short8 afr[4][4];                 // A[m=lane&15][k=(lane>>4)*8+j]
    #pragma unroll
    for (int mi = 0; mi < 4; ++mi) {
        int gate = 16 * (w + 8 * mi) + cn;
        #pragma unroll
        for (int kt = 0; kt < 4; ++kt) {
            const float* p = wih + (size_t)gate * 128 + kt * 32 + rg * 8;
            float4 f0 = *(const float4*)p;
            float4 f1 = *(const float4*)(p + 4);
            union { short8 v; u32 u[4]; } sv;
            sv.u[0] = pack_bf16(f0.x, f0.y);
            sv.u[1] = pack_bf16(f0.z, f0.w);
            sv.u[2] = pack_bf16(f1.x, f1.y);
            sv.u[3] = pack_bf16(f1.z, f1.w);
            afr[mi][kt] = sv.v;
        }
    }
    float bs[4][4];
    #pragma unroll
    for (int mi = 0; mi < 4; ++mi)
        #pragma unroll
        for (int r = 0; r < 4; ++r) {
            int g = 16 * (w + 8 * mi) + 4 * rg + r;
            bs[mi][r] = bih[g] + bhh[g];
        }

    __shared__ int toks[128];
    __shared__ u16 tile[8][16][136];
    if (tid < 128)
        toks[tid] = sent[(sc * 8 + (tid >> 4)) * 64 + g4 * 16 + (tid & 15)];
    __syncthreads();
    {
        int rr = tid >> 2, q = tid & 3;
        int ss = rr >> 4, nn = rr & 15;
        const float* er = emb + (size_t)toks[rr] * 128 + q * 32;
        u16* dst = &tile[ss][nn][q * 32];
        #pragma unroll
        for (int u = 0; u < 4; ++u) {
            float4 a = *(const float4*)(er + u * 8);
            float4 c = *(const float4*)(er + u * 8 + 4);
            uint4 st;
            st.x = pack_bf16(a.x, a.y); st.y = pack_bf16(a.z, a.w);
            st.z = pack_bf16(c.x, c.y); st.w = pack_bf16(c.z, c.w);
            *(uint4*)(dst + u * 8) = st;
        }
    }
    __syncthreads();

    for (int ss = 0; ss < 8; ++ss) {
        short8 bfr[4];
        #pragma unroll
        for (int kt = 0; kt < 4; ++kt)
            bfr[kt] = *(const short8*)&tile[ss][cn][kt * 32 + rg * 8];
        int s = sc * 8 + ss;
        #pragma unroll
        for (int mi = 0; mi < 4; ++mi) {
            f32x4 acc = {0.f, 0.f, 0.f, 0.f};
            #pragma unroll
            for (int kt = 0; kt < 4; ++kt)
                acc = __builtin_amdgcn_mfma_f32_16x16x32_bf16(afr[mi][kt], bfr[kt], acc, 0, 0, 0);
            size_t base = (((size_t)s * 4 + g4) * 32 + (w + 8 * mi)) * 256
                        + (size_t)rg * 64 + (size_t)cn * 4;
            uint2 st;
            st.x = pack_bf16((acc[0] + bs[mi][0]) * LOG2E, (acc[1] + bs[mi][1]) * LOG2E);
            st.y = pack_bf16((acc[2] + bs[mi][2]) * LOG2E, (acc[3] + bs[mi][3]) * LOG2E);
            *(uint2*)(X + base) = st;
        }
    }
}

// ---------------------------------------------------------------------------
// K2: bidirectional LSTM recurrence.  8 blocks = 2 dirs x 4 batch-groups(16).
// W_hh (pre-scaled by log2e) in per-wave A-fragments; h via double-buffered
// LDS tile; c in registers.  In-loop barrier is LDS-ONLY
// (s_waitcnt lgkmcnt(0); s_barrier) so the depth-2 global X prefetch stays in
// flight across steps — __syncthreads would drain vmcnt(0) every step.
// ---------------------------------------------------------------------------
__global__ __launch_bounds__(512) void k_lstm(
    const float* __restrict__ h0, const float* __restrict__ c0,
    const float* __restrict__ whhf, const float* __restrict__ whhb,
    const u16* __restrict__ Xf, const u16* __restrict__ Xb,
    u16* __restrict__ hfo, u16* __restrict__ hbo)
{
    int d  = blockIdx.x >> 2, g4 = blockIdx.x & 3;
    const float* whh = d ? whhb : whhf;
    const u16*   X   = d ? Xb   : Xf;
    u16*         ho  = d ? hbo  : hfo;
    int w = threadIdx.x >> 6, lane = threadIdx.x & 63;
    int rg = lane >> 4, cn = lane & 15;

    short8 afr[4][4];                  // whh * log2e, A-frag layout
    #pragma unroll
    for (int mi = 0; mi < 4; ++mi) {
        int gate = 16 * (w + 8 * mi) + cn;
        #pragma unroll
        for (int kt = 0; kt < 4; ++kt) {
            const float* p = whh + (size_t)gate * 128 + kt * 32 + rg * 8;
            float4 f0 = *(const float4*)p;
            float4 f1 = *(const float4*)(p + 4);
            union { short8 v; u32 u[4]; } sv;
            sv.u[0] = pack_bf16(f0.x * LOG2E, f0.y * LOG2E);
            sv.u[1] = pack_bf16(f0.z * LOG2E, f0.w * LOG2E);
            sv.u[2] = pack_bf16(f1.x * LOG2E, f1.y * LOG2E);
            sv.u[3] = pack_bf16(f1.z * LOG2E, f1.w * LOG2E);
            afr[mi][kt] = sv.v;
        }
    }
    int b = g4 * 16 + cn;
    int chb = 16 * w + rg * 4;
    float cst[4];
    {
        float4 cv = *(const float4*)(c0 + ((size_t)d * 64 + b) * 128 + chb);
        cst[0]=cv.x; cst[1]=cv.y; cst[2]=cv.z; cst[3]=cv.w;
    }
    __shared__ u16 hbuf[2][16][136];
    {
        float4 hv = *(const float4*)(h0 + ((size_t)d * 64 + b) * 128 + chb);
        uint2 st0;
        st0.x = pack_bf16(hv.x, hv.y);
        st0.y = pack_bf16(hv.z, hv.w);
        *(uint2*)&hbuf[0][cn][chb] = st0;
    }
    __syncthreads();

    int s0 = d ? 511 : 0;
    const int sdelta = d ? -32768 : 32768;      // X u16 elems per s-step
    const ptrdiff_t hdelta = d ? -8192 : 8192;  // 64*128 u16 per s-step
    size_t lof = (size_t)rg * 64 + (size_t)cn * 4;

    // depth-2 X pipeline: xc = step t, xn = step t+1, issue t+2 each iter.
    // Over/under-runs land harmlessly inside the other X buffer in d_ws.
    const u16* xp[4];
    uint2 xc[4], xn[4];
    #pragma unroll
    for (int mi = 0; mi < 4; ++mi) {
        xp[mi] = X + (((size_t)s0 * 4 + g4) * 32 + (w + 8 * mi)) * 256 + lof;
        xc[mi] = *(const uint2*)xp[mi];
        xp[mi] += sdelta;
        xn[mi] = *(const uint2*)xp[mi];
        xp[mi] += sdelta;
    }
    u16* hop = ho + ((size_t)s0 * 64 + b) * 128 + chb;
    const u16* hr0 = &hbuf[0][cn][0];
    const u16* hr1 = &hbuf[1][cn][0];
    u16* hw0 = &hbuf[0][cn][chb];
    u16* hw1 = &hbuf[1][cn][chb];

    for (int t = 0; t < 512; ++t) {
        uint2 x2[4];                            // issue prefetch for t+2
        #pragma unroll
        for (int mi = 0; mi < 4; ++mi) {
            x2[mi] = *(const uint2*)xp[mi];
            xp[mi] += sdelta;
        }
        int cur = t & 1;
        const u16* rrow = cur ? hr1 : hr0;
        short8 bfr[4];
        #pragma unroll
        for (int kt = 0; kt < 4; ++kt)
            bfr[kt] = *(const short8*)(rrow + kt * 32 + rg * 8);

        f32x4 z[4];
        #pragma unroll
        for (int mi = 0; mi < 4; ++mi) {
            f32x4 acc = {0.f, 0.f, 0.f, 0.f};
            #pragma unroll
            for (int kt = 0; kt < 4; ++kt)
                acc = __builtin_amdgcn_mfma_f32_16x16x32_bf16(afr[mi][kt], bfr[kt], acc, 0, 0, 0);
            z[mi] = acc;
        }

        float hnew[4];
        #pragma unroll
        for (int r = 0; r < 4; ++r) {
            // z and X are pre-scaled by log2e: sigmoids/tanh via raw exp2.
            float zi = z[0][r] + xex(xc[0], r);
            float zf = z[1][r] + xex(xc[1], r);
            float zg = z[2][r] + xex(xc[2], r);
            float zo = z[3][r] + xex(xc[3], r);
            float ei = fexp2(-zi);
            float ef = fexp2(-zf);
            float eo = fexp2(-zo);
            float eg = fexp2(fminf(zg + zg, 115.f));
            float A = 1.f + ei, F = 1.f + ef, G = eg + 1.f, O = 1.f + eo;
            float AG = A * G;
            // c' = c*sig(zf) + sig(zi)*tanh(zg) = (c*A*G + (eg-1)*F)/(F*A*G)
            float cc = (cst[r] * AG + (eg - 1.f) * F) * frcp(F * AG);
            cst[r] = cc;
            float ec = fexp2(fminf(2.885390082f * cc, 115.f));   // 2^(2c*log2e)
            hnew[r] = (ec - 1.f) * frcp(O * (ec + 1.f));         // sig(zo)*tanh(c')
        }
        uint2 st;
        st.x = pack_bf16(hnew[0], hnew[1]);
        st.y = pack_bf16(hnew[2], hnew[3]);
        u16* wrow = cur ? hw0 : hw1;            // write the OTHER buffer
        *(uint2*)wrow = st;
        *(uint2*)hop = st;                      // global h (never drained in-loop)
        hop += hdelta;
        // LDS-only barrier: drain ds ops, leave global loads/stores in flight.
        asm volatile("s_waitcnt lgkmcnt(0)\n\ts_barrier" ::: "memory");
        #pragma unroll
        for (int mi = 0; mi < 4; ++mi) { xc[mi] = xn[mi]; xn[mi] = x2[mi]; }
    }
}

// ---------------------------------------------------------------------------
// K3: feats[s,b,t] = [hf|hb] . w_out[t] + b_out[t].   block handles 32 pos.
// ---------------------------------------------------------------------------
__global__ __launch_bounds__(256) void k_feats(
    const u16* __restrict__ hf, const u16* __restrict__ hb,
    const float* __restrict__ wout, const float* __restrict__ bout,
    float* __restrict__ feats)
{
    __shared__ u16 sf[32][136], sb[32][136];
    __shared__ float wo[7][260];
    __shared__ float bo[8];
    int tid = threadIdx.x;
    int pos0 = blockIdx.x * 32;
    {
        int r = tid >> 3, cc = (tid & 7) * 16;
        const uint4* pf = (const uint4*)(hf + (size_t)(pos0 + r) * 128 + cc);
        const uint4* pb = (const uint4*)(hb + (size_t)(pos0 + r) * 128 + cc);
        *(uint4*)&sf[r][cc]     = pf[0];
        *(uint4*)&sf[r][cc + 8] = pf[1];
        *(uint4*)&sb[r][cc]     = pb[0];
        *(uint4*)&sb[r][cc + 8] = pb[1];
    }
    for (int i = tid; i < 1792; i += 256) wo[i >> 8][i & 255] = wout[i];
    if (tid < 7) bo[tid] = bout[tid];
    __syncthreads();
    int pp = tid >> 3, tt = tid & 7;
    if (tt < 7) {
        float acc = bo[tt];
        #pragma unroll 4
        for (int ch = 0; ch < 128; ++ch)
            acc += bf2f(sf[pp][ch]) * wo[tt][ch]
                 + bf2f(sb[pp][ch]) * wo[tt][128 + ch];
        feats[(size_t)(pos0 + pp) * 7 + tt] = acc;
    }
}

// ---------------------------------------------------------------------------
// K4a: CRF chunk fold.  block=(b, chunk of 64 steps).
// ---------------------------------------------------------------------------
__global__ __launch_bounds__(64) void k_crf_chunk(
    const float* __restrict__ feats, const float* __restrict__ trans,
    float* __restrict__ chunkM)
{
    int b = blockIdx.x >> 3, c = blockIdx.x & 7;
    int lane = threadIdx.x;
    int i = lane >> 3, j = lane & 7;
    __shared__ float M[8][8];
    __shared__ float fl[64][8];
    int s0 = c * 64;
    for (int idx = lane; idx < 448; idx += 64) {
        int ss = idx / 7, jj = idx - ss * 7;
        fl[ss][jj] = feats[(size_t)((s0 + ss) * 64 + b) * 7 + jj];
    }
    float tc[7];
    #pragma unroll
    for (int k = 0; k < 7; ++k) tc[k] = (j < 7) ? trans[k * 7 + j] : 0.f;
    __syncthreads();
    M[i][j] = (i < 7 && j < 7) ? (trans[i * 7 + j] + fl[0][j]) : -1e30f;
    __syncthreads();
    for (int ss = 1; ss < 64; ++ss) {
        float4 m0 = *(const float4*)&M[i][0];
        float4 m1 = *(const float4*)&M[i][4];
        float v0 = m0.x + tc[0], v1 = m0.y + tc[1], v2 = m0.z + tc[2];
        float v3 = m0.w + tc[3], v4 = m1.x + tc[4], v5 = m1.y + tc[5];
        float v6 = m1.z + tc[6];
        float mx = fmaxf(fmaxf(fmaxf(v0, v1), fmaxf(v2, v3)),
                         fmaxf(fmaxf(v4, v5), v6));
        float sm = __expf(v0 - mx) + __expf(v1 - mx) + __expf(v2 - mx)
                 + __expf(v3 - mx) + __expf(v4 - mx) + __expf(v5 - mx)
                 + __expf(v6 - mx);
        float r = mx + __logf(sm) + fl[ss][j];
        __syncthreads();
        if (i < 7 && j < 7) M[i][j] = r;
        __syncthreads();
    }
    if (i < 7 && j < 7)
        chunkM[(size_t)(b * 8 + c) * 49 + i * 7 + j] = M[i][j];
}

// ---------------------------------------------------------------------------
// K4b: fold 8 chunk matrices + alpha0 + STOP row; gold score; atomicAdd.
// ---------------------------------------------------------------------------
__global__ __launch_bounds__(64) void k_crf_final(
    const float* __restrict__ chunkM, const float* __restrict__ trans,
    const int* __restrict__ tags, const float* __restrict__ feats,
    float* __restrict__ out)
{
    int b = blockIdx.x;
    int lane = threadIdx.x;
    __shared__ float P[8][49];
    __shared__ float Tl[49];
    __shared__ float av[2][8];
    __shared__ int   tg[512];
    for (int idx = lane; idx < 392; idx += 64)
        P[idx / 49][idx % 49] = chunkM[(size_t)b * 392 + idx];
    if (lane < 49) Tl[lane] = trans[lane];
    for (int idx = lane; idx < 512; idx += 64) tg[idx] = tags[(size_t)b * 512 + idx];
    if (lane < 8) av[0][lane] = (lane == 5) ? 0.f : -1e4f;
    __syncthreads();
    int cur = 0;
    for (int cch = 0; cch < 8; ++cch) {
        if (lane < 7) {
            float vv[7], mx = -1e30f;
            #pragma unroll
            for (int ii = 0; ii < 7; ++ii) {
                vv[ii] = av[cur][ii] + P[cch][ii * 7 + lane];
                mx = fmaxf(mx, vv[ii]);
            }
            float sm = 0.f;
            #pragma unroll
            for (int ii = 0; ii < 7; ++ii) sm += __expf(vv[ii] - mx);
            av[cur ^ 1][lane] = mx + __logf(sm);
        }
        __syncthreads();
        cur ^= 1;
    }
    float mx = -1e30f, uu[7];
    #pragma unroll
    for (int jj = 0; jj < 7; ++jj) {
        uu[jj] = av[cur][jj] + Tl[6 * 7 + jj];
        mx = fmaxf(mx, uu[jj]);
    }
    float sm = 0.f;
    #pragma unroll
    for (int jj = 0; jj < 7; ++jj) sm += __expf(uu[jj] - mx);
    float fwd = mx + __logf(sm);
    float acc = 0.f;
    for (int ss = lane; ss < 512; ss += 64) {
        int tn = tg[ss];
        int tp = (ss == 0) ? 5 : tg[ss - 1];
        acc += Tl[tn * 7 + tp] + feats[(size_t)(ss * 64 + b) * 7 + tn];
    }
    #pragma unroll
    for (int mk = 32; mk >= 1; mk >>= 1) acc += __shfl_xor(acc, mk, 64);
    if (lane == 0) {
        float gold = acc + Tl[6 * 7 + tg[511]];
        atomicAdd(out, (fwd - gold) * (1.0f / 64.0f));
    }
}

// ---------------------------------------------------------------------------
extern "C" void kernel_launch(void* const* d_in, const int* in_sizes, int n_in,
                              void* d_out, int out_size, void* d_ws, size_t ws_size,
                              hipStream_t stream) {
    const int*   sent = (const int*)d_in[0];
    const int*   tags = (const int*)d_in[1];
    const float* h0   = (const float*)d_in[2];
    const float* c0   = (const float*)d_in[3];
    const float* emb  = (const float*)d_in[4];
    const float* wihf = (const float*)d_in[5];
    const float* whhf = (const float*)d_in[6];
    const float* bihf = (const float*)d_in[7];
    const float* bhhf = (const float*)d_in[8];
    const float* wihb = (const float*)d_in[9];
    const float* whhb = (const float*)d_in[10];
    const float* bihb = (const float*)d_in[11];
    const float* bhhb = (const float*)d_in[12];
    const float* wout = (const float*)d_in[13];
    const float* bout = (const float*)d_in[14];
    const float* trn  = (const float*)d_in[15];

    char* ws = (char*)d_ws;
    u16*   Xf     = (u16*)(ws);                       // 33,554,432 B
    u16*   Xb     = (u16*)(ws + 33554432);            // 33,554,432 B
    u16*   hfp    = (u16*)(ws + 67108864);            //  8,388,608 B
    u16*   hbp    = (u16*)(ws + 75497472);            //  8,388,608 B
    float* feats  = (float*)(ws + 83886080);          //    917,504 B
    float* chunkM = (float*)(ws + 84803584);          //    100,352 B

    hipMemsetAsync(d_out, 0, 4, stream);
    k_inproj2<<<512, 512, 0, stream>>>(sent, emb, wihf, bihf, bhhf,
                                       wihb, bihb, bhhb, Xf, Xb);
    k_lstm<<<8, 512, 0, stream>>>(h0, c0, whhf, whhb, Xf, Xb, hfp, hbp);
    k_feats<<<1024, 256, 0, stream>>>(hfp, hbp, wout, bout, feats);
    k_crf_chunk<<<512, 64, 0, stream>>>(feats, trn, chunkM);
    k_crf_final<<<64, 64, 0, stream>>>(chunkM, trn, tags, feats, (float*)d_out);
}

// Round 4
// 576.775 us; speedup vs baseline: 1.2780x; 1.2780x over previous
//
#include <hip/hip_runtime.h>

typedef unsigned int u32;
typedef unsigned short u16;
typedef __attribute__((ext_vector_type(8))) short short8;   // 8 bf16 (4 VGPRs)
typedef __attribute__((ext_vector_type(4))) float f32x4;

#define DEV __device__ __forceinline__
#define LOG2E 1.44269504089f

DEV u16 f2bf(float f) {
    u32 u = __float_as_uint(f);
    return (u16)((u + 0x7FFFu + ((u >> 16) & 1u)) >> 16);
}
DEV float bf2f(u16 h) { return __uint_as_float(((u32)h) << 16); }
DEV float frcp(float x) { return __builtin_amdgcn_rcpf(x); }
DEV float fexp2(float x) {
#if __has_builtin(__builtin_amdgcn_exp2f)
    return __builtin_amdgcn_exp2f(x);
#else
    return exp2f(x);
#endif
}
DEV u32 pack_bf16(float a, float b) {
#if __has_builtin(__builtin_amdgcn_cvt_pk_bf16_f32)
    auto v = __builtin_amdgcn_cvt_pk_bf16_f32(a, b);   // lo=a, hi=b
    u32 r; __builtin_memcpy(&r, &v, 4); return r;
#else
    return (u32)f2bf(a) | ((u32)f2bf(b) << 16);
#endif
}
// extract r-th bf16 (r constant under unroll) from packed uint2
DEV float xex(uint2 v, int r) {
    u32 u = (r & 2) ? v.y : v.x;
    return (r & 1) ? __uint_as_float(u & 0xFFFF0000u) : __uint_as_float(u << 16);
}

// ---------------------------------------------------------------------------
// K1: fused embedding gather + input projection, MFMA, both dirs.
// Output X is PRE-SCALED by log2e so k_lstm uses raw v_exp (base-2).
// ---------------------------------------------------------------------------
__global__ __launch_bounds__(512) void k_inproj2(
    const int* __restrict__ sent, const float* __restrict__ emb,
    const float* __restrict__ wihf, const float* __restrict__ bihf, const float* __restrict__ bhhf,
    const float* __restrict__ wihb, const float* __restrict__ bihb, const float* __restrict__ bhhb,
    u16* __restrict__ Xf, u16* __restrict__ Xb)
{
    int blk = blockIdx.x;
    int d  = blk >> 8;
    int g4 = (blk >> 6) & 3;
    int sc = blk & 63;
    const float* wih = d ? wihb : wihf;
    const float* bih = d ? bihb : bihf;
    const float* bhh = d ? bhhb : bhhf;
    u16* X = d ? Xb : Xf;
    int tid = threadIdx.x;
    int w = tid >> 6, lane = tid & 63;
    int rg = lane >> 4, cn = lane & 15;

    short8 afr[4][4];                 // A[m=lane&15][k=(lane>>4)*8+j]
    #pragma unroll
    for (int mi = 0; mi < 4; ++mi) {
        int gate = 16 * (w + 8 * mi) + cn;
        #pragma unroll
        for (int kt = 0; kt < 4; ++kt) {
            const float* p = wih + (size_t)gate * 128 + kt * 32 + rg * 8;
            float4 f0 = *(const float4*)p;
            float4 f1 = *(const float4*)(p + 4);
            union { short8 v; u32 u[4]; } sv;
            sv.u[0] = pack_bf16(f0.x, f0.y);
            sv.u[1] = pack_bf16(f0.z, f0.w);
            sv.u[2] = pack_bf16(f1.x, f1.y);
            sv.u[3] = pack_bf16(f1.z, f1.w);
            afr[mi][kt] = sv.v;
        }
    }
    float bs[4][4];
    #pragma unroll
    for (int mi = 0; mi < 4; ++mi)
        #pragma unroll
        for (int r = 0; r < 4; ++r) {
            int g = 16 * (w + 8 * mi) + 4 * rg + r;
            bs[mi][r] = bih[g] + bhh[g];
        }

    __shared__ int toks[128];
    __shared__ u16 tile[8][16][136];
    if (tid < 128)
        toks[tid] = sent[(sc * 8 + (tid >> 4)) * 64 + g4 * 16 + (tid & 15)];
    __syncthreads();
    {
        int rr = tid >> 2, q = tid & 3;
        int ss = rr >> 4, nn = rr & 15;
        const float* er = emb + (size_t)toks[rr] * 128 + q * 32;
        u16* dst = &tile[ss][nn][q * 32];
        #pragma unroll
        for (int u = 0; u < 4; ++u) {
            float4 a = *(const float4*)(er + u * 8);
            float4 c = *(const float4*)(er + u * 8 + 4);
            uint4 st;
            st.x = pack_bf16(a.x, a.y); st.y = pack_bf16(a.z, a.w);
            st.z = pack_bf16(c.x, c.y); st.w = pack_bf16(c.z, c.w);
            *(uint4*)(dst + u * 8) = st;
        }
    }
    __syncthreads();

    for (int ss = 0; ss < 8; ++ss) {
        short8 bfr[4];
        #pragma unroll
        for (int kt = 0; kt < 4; ++kt)
            bfr[kt] = *(const short8*)&tile[ss][cn][kt * 32 + rg * 8];
        int s = sc * 8 + ss;
        #pragma unroll
        for (int mi = 0; mi < 4; ++mi) {
            f32x4 acc = {0.f, 0.f, 0.f, 0.f};
            #pragma unroll
            for (int kt = 0; kt < 4; ++kt)
                acc = __builtin_amdgcn_mfma_f32_16x16x32_bf16(afr[mi][kt], bfr[kt], acc, 0, 0, 0);
            size_t base = (((size_t)s * 4 + g4) * 32 + (w + 8 * mi)) * 256
                        + (size_t)rg * 64 + (size_t)cn * 4;
            uint2 st;
            st.x = pack_bf16((acc[0] + bs[mi][0]) * LOG2E, (acc[1] + bs[mi][1]) * LOG2E);
            st.y = pack_bf16((acc[2] + bs[mi][2]) * LOG2E, (acc[3] + bs[mi][3]) * LOG2E);
            *(uint2*)(X + base) = st;
        }
    }
}

// ---------------------------------------------------------------------------
// K2: bidirectional LSTM recurrence.  8 blocks = 2 dirs x 4 batch-groups(16).
// R4 rewrite: t unrolled by 2 (static LDS ping-pong, no selects/rotation),
// MFMA accumulator initialized from X (no zero-init, no post-add), two
// independent use-then-reload X register sets (depth-2 prefetch, no moves),
// global h-store BEFORE the barrier (R1-empirical), LDS-only barrier.
// ---------------------------------------------------------------------------
__global__ __launch_bounds__(512) void k_lstm(
    const float* __restrict__ h0, const float* __restrict__ c0,
    const float* __restrict__ whhf, const float* __restrict__ whhb,
    const u16* __restrict__ Xf, const u16* __restrict__ Xb,
    u16* __restrict__ hfo, u16* __restrict__ hbo)
{
    int d  = blockIdx.x >> 2, g4 = blockIdx.x & 3;
    const float* whh = d ? whhb : whhf;
    const u16*   X   = d ? Xb   : Xf;
    u16*         ho  = d ? hbo  : hfo;
    int w = threadIdx.x >> 6, lane = threadIdx.x & 63;
    int rg = lane >> 4, cn = lane & 15;

    short8 afr[4][4];                  // whh * log2e, A-frag layout
    #pragma unroll
    for (int mi = 0; mi < 4; ++mi) {
        int gate = 16 * (w + 8 * mi) + cn;
        #pragma unroll
        for (int kt = 0; kt < 4; ++kt) {
            const float* p = whh + (size_t)gate * 128 + kt * 32 + rg * 8;
            float4 f0 = *(const float4*)p;
            float4 f1 = *(const float4*)(p + 4);
            union { short8 v; u32 u[4]; } sv;
            sv.u[0] = pack_bf16(f0.x * LOG2E, f0.y * LOG2E);
            sv.u[1] = pack_bf16(f0.z * LOG2E, f0.w * LOG2E);
            sv.u[2] = pack_bf16(f1.x * LOG2E, f1.y * LOG2E);
            sv.u[3] = pack_bf16(f1.z * LOG2E, f1.w * LOG2E);
            afr[mi][kt] = sv.v;
        }
    }
    int b = g4 * 16 + cn;
    int chb = 16 * w + rg * 4;
    float cst[4];
    {
        float4 cv = *(const float4*)(c0 + ((size_t)d * 64 + b) * 128 + chb);
        cst[0]=cv.x; cst[1]=cv.y; cst[2]=cv.z; cst[3]=cv.w;
    }
    __shared__ u16 hbuf[2][16][136];
    {
        float4 hv = *(const float4*)(h0 + ((size_t)d * 64 + b) * 128 + chb);
        uint2 st0;
        st0.x = pack_bf16(hv.x, hv.y);
        st0.y = pack_bf16(hv.z, hv.w);
        *(uint2*)&hbuf[0][cn][chb] = st0;
    }
    __syncthreads();

    int s0 = d ? 511 : 0;
    const int sdelta = d ? -32768 : 32768;      // X u16 elems per s-step
    const ptrdiff_t hdelta = d ? -8192 : 8192;  // 64*128 u16 per s-step
    size_t lof = (size_t)rg * 64 + (size_t)cn * 4;

    // Two X register sets: xA serves even substeps, xB odd.  Each is consumed
    // then reloaded IN PLACE for t+2 (no rotation movs).  Pointer over/under-
    // runs at the tail land harmlessly inside the other X buffer in d_ws.
    const u16* pa[4]; const u16* pb[4];
    uint2 xA[4], xB[4];
    #pragma unroll
    for (int mi = 0; mi < 4; ++mi) {
        const u16* base = X + (((size_t)s0 * 4 + g4) * 32 + (w + 8 * mi)) * 256 + lof;
        xA[mi] = *(const uint2*)base;
        xB[mi] = *(const uint2*)(base + sdelta);
        pa[mi] = base + 2 * sdelta;
        pb[mi] = base + 3 * sdelta;
    }
    u16* hop = ho + ((size_t)s0 * 64 + b) * 128 + chb;

    // One recurrence substep: read hbuf[RB], write hbuf[WB]; consume XC,
    // reload it for t+2 from XP (advancing XP by 2 steps).
#define LSTM_STEP(RB, WB, XC, XP)                                            \
    do {                                                                     \
        short8 bfr[4];                                                       \
        _Pragma("unroll")                                                    \
        for (int kt = 0; kt < 4; ++kt)                                       \
            bfr[kt] = *(const short8*)&hbuf[RB][cn][kt * 32 + rg * 8];       \
        f32x4 z[4];                                                          \
        _Pragma("unroll")                                                    \
        for (int mi = 0; mi < 4; ++mi) {                                     \
            f32x4 acc;                                                       \
            acc[0] = xex(XC[mi], 0); acc[1] = xex(XC[mi], 1);                \
            acc[2] = xex(XC[mi], 2); acc[3] = xex(XC[mi], 3);                \
            _Pragma("unroll")                                                \
            for (int kt = 0; kt < 4; ++kt)                                   \
                acc = __builtin_amdgcn_mfma_f32_16x16x32_bf16(               \
                    afr[mi][kt], bfr[kt], acc, 0, 0, 0);                     \
            z[mi] = acc;                                                     \
            XC[mi] = *(const uint2*)XP[mi];                                  \
            XP[mi] += 2 * sdelta;                                            \
        }                                                                    \
        float hnew[4];                                                       \
        _Pragma("unroll")                                                    \
        for (int r = 0; r < 4; ++r) {                                        \
            float zi = z[0][r], zf = z[1][r], zg = z[2][r], zo = z[3][r];    \
            float ei = fexp2(-zi);                                           \
            float ef = fexp2(-zf);                                           \
            float eo = fexp2(-zo);                                           \
            float eg = fexp2(fminf(zg + zg, 115.f));                         \
            float A = 1.f + ei, F = 1.f + ef, G = eg + 1.f, O = 1.f + eo;    \
            float AG = A * G;                                                \
            float cc = (cst[r] * AG + (eg - 1.f) * F) * frcp(F * AG);        \
            cst[r] = cc;                                                     \
            float ec = fexp2(fminf(2.885390082f * cc, 115.f));               \
            hnew[r] = (ec - 1.f) * frcp(O * (ec + 1.f));                     \
        }                                                                    \
        uint2 st;                                                            \
        st.x = pack_bf16(hnew[0], hnew[1]);                                  \
        st.y = pack_bf16(hnew[2], hnew[3]);                                  \
        *(uint2*)&hbuf[WB][cn][chb] = st;                                    \
        *(uint2*)hop = st;                                                   \
        hop += hdelta;                                                       \
        asm volatile("s_waitcnt lgkmcnt(0)\n\ts_barrier" ::: "memory");      \
    } while (0)

    for (int it = 0; it < 256; ++it) {
        LSTM_STEP(0, 1, xA, pa);
        LSTM_STEP(1, 0, xB, pb);
    }
#undef LSTM_STEP
}

// ---------------------------------------------------------------------------
// K3: feats[s,b,t] = [hf|hb] . w_out[t] + b_out[t].   block handles 32 pos.
// ---------------------------------------------------------------------------
__global__ __launch_bounds__(256) void k_feats(
    const u16* __restrict__ hf, const u16* __restrict__ hb,
    const float* __restrict__ wout, const float* __restrict__ bout,
    float* __restrict__ feats)
{
    __shared__ u16 sf[32][136], sb[32][136];
    __shared__ float wo[7][260];
    __shared__ float bo[8];
    int tid = threadIdx.x;
    int pos0 = blockIdx.x * 32;
    {
        int r = tid >> 3, cc = (tid & 7) * 16;
        const uint4* pf = (const uint4*)(hf + (size_t)(pos0 + r) * 128 + cc);
        const uint4* pb = (const uint4*)(hb + (size_t)(pos0 + r) * 128 + cc);
        *(uint4*)&sf[r][cc]     = pf[0];
        *(uint4*)&sf[r][cc + 8] = pf[1];
        *(uint4*)&sb[r][cc]     = pb[0];
        *(uint4*)&sb[r][cc + 8] = pb[1];
    }
    for (int i = tid; i < 1792; i += 256) wo[i >> 8][i & 255] = wout[i];
    if (tid < 7) bo[tid] = bout[tid];
    __syncthreads();
    int pp = tid >> 3, tt = tid & 7;
    if (tt < 7) {
        float acc = bo[tt];
        #pragma unroll 4
        for (int ch = 0; ch < 128; ++ch)
            acc += bf2f(sf[pp][ch]) * wo[tt][ch]
                 + bf2f(sb[pp][ch]) * wo[tt][128 + ch];
        feats[(size_t)(pos0 + pp) * 7 + tt] = acc;
    }
}

// ---------------------------------------------------------------------------
// K4a: CRF chunk fold.  block=(b, chunk of 64 steps).
// ---------------------------------------------------------------------------
__global__ __launch_bounds__(64) void k_crf_chunk(
    const float* __restrict__ feats, const float* __restrict__ trans,
    float* __restrict__ chunkM)
{
    int b = blockIdx.x >> 3, c = blockIdx.x & 7;
    int lane = threadIdx.x;
    int i = lane >> 3, j = lane & 7;
    __shared__ float M[8][8];
    __shared__ float fl[64][8];
    int s0 = c * 64;
    for (int idx = lane; idx < 448; idx += 64) {
        int ss = idx / 7, jj = idx - ss * 7;
        fl[ss][jj] = feats[(size_t)((s0 + ss) * 64 + b) * 7 + jj];
    }
    float tc[7];
    #pragma unroll
    for (int k = 0; k < 7; ++k) tc[k] = (j < 7) ? trans[k * 7 + j] : 0.f;
    __syncthreads();
    M[i][j] = (i < 7 && j < 7) ? (trans[i * 7 + j] + fl[0][j]) : -1e30f;
    __syncthreads();
    for (int ss = 1; ss < 64; ++ss) {
        float4 m0 = *(const float4*)&M[i][0];
        float4 m1 = *(const float4*)&M[i][4];
        float v0 = m0.x + tc[0], v1 = m0.y + tc[1], v2 = m0.z + tc[2];
        float v3 = m0.w + tc[3], v4 = m1.x + tc[4], v5 = m1.y + tc[5];
        float v6 = m1.z + tc[6];
        float mx = fmaxf(fmaxf(fmaxf(v0, v1), fmaxf(v2, v3)),
                         fmaxf(fmaxf(v4, v5), v6));
        float sm = __expf(v0 - mx) + __expf(v1 - mx) + __expf(v2 - mx)
                 + __expf(v3 - mx) + __expf(v4 - mx) + __expf(v5 - mx)
                 + __expf(v6 - mx);
        float r = mx + __logf(sm) + fl[ss][j];
        __syncthreads();
        if (i < 7 && j < 7) M[i][j] = r;
        __syncthreads();
    }
    if (i < 7 && j < 7)
        chunkM[(size_t)(b * 8 + c) * 49 + i * 7 + j] = M[i][j];
}

// ---------------------------------------------------------------------------
// K4b: fold 8 chunk matrices + alpha0 + STOP row; gold score; atomicAdd.
// ---------------------------------------------------------------------------
__global__ __launch_bounds__(64) void k_crf_final(
    const float* __restrict__ chunkM, const float* __restrict__ trans,
    const int* __restrict__ tags, const float* __restrict__ feats,
    float* __restrict__ out)
{
    int b = blockIdx.x;
    int lane = threadIdx.x;
    __shared__ float P[8][49];
    __shared__ float Tl[49];
    __shared__ float av[2][8];
    __shared__ int   tg[512];
    for (int idx = lane; idx < 392; idx += 64)
        P[idx / 49][idx % 49] = chunkM[(size_t)b * 392 + idx];
    if (lane < 49) Tl[lane] = trans[lane];
    for (int idx = lane; idx < 512; idx += 64) tg[idx] = tags[(size_t)b * 512 + idx];
    if (lane < 8) av[0][lane] = (lane == 5) ? 0.f : -1e4f;
    __syncthreads();
    int cur = 0;
    for (int cch = 0; cch < 8; ++cch) {
        if (lane < 7) {
            float vv[7], mx = -1e30f;
            #pragma unroll
            for (int ii = 0; ii < 7; ++ii) {
                vv[ii] = av[cur][ii] + P[cch][ii * 7 + lane];
                mx = fmaxf(mx, vv[ii]);
            }
            float sm = 0.f;
            #pragma unroll
            for (int ii = 0; ii < 7; ++ii) sm += __expf(vv[ii] - mx);
            av[cur ^ 1][lane] = mx + __logf(sm);
        }
        __syncthreads();
        cur ^= 1;
    }
    float mx = -1e30f, uu[7];
    #pragma unroll
    for (int jj = 0; jj < 7; ++jj) {
        uu[jj] = av[cur][jj] + Tl[6 * 7 + jj];
        mx = fmaxf(mx, uu[jj]);
    }
    float sm = 0.f;
    #pragma unroll
    for (int jj = 0; jj < 7; ++jj) sm += __expf(uu[jj] - mx);
    float fwd = mx + __logf(sm);
    float acc = 0.f;
    for (int ss = lane; ss < 512; ss += 64) {
        int tn = tg[ss];
        int tp = (ss == 0) ? 5 : tg[ss - 1];
        acc += Tl[tn * 7 + tp] + feats[(size_t)(ss * 64 + b) * 7 + tn];
    }
    #pragma unroll
    for (int mk = 32; mk >= 1; mk >>= 1) acc += __shfl_xor(acc, mk, 64);
    if (lane == 0) {
        float gold = acc + Tl[6 * 7 + tg[511]];
        atomicAdd(out, (fwd - gold) * (1.0f / 64.0f));
    }
}

// ---------------------------------------------------------------------------
extern "C" void kernel_launch(void* const* d_in, const int* in_sizes, int n_in,
                              void* d_out, int out_size, void* d_ws, size_t ws_size,
                              hipStream_t stream) {
    const int*   sent = (const int*)d_in[0];
    const int*   tags = (const int*)d_in[1];
    const float* h0   = (const float*)d_in[2];
    const float* c0   = (const float*)d_in[3];
    const float* emb  = (const float*)d_in[4];
    const float* wihf = (const float*)d_in[5];
    const float* whhf = (const float*)d_in[6];
    const float* bihf = (const float*)d_in[7];
    const float* bhhf = (const float*)d_in[8];
    const float* wihb = (const float*)d_in[9];
    const float* whhb = (const float*)d_in[10];
    const float* bihb = (const float*)d_in[11];
    const float* bhhb = (const float*)d_in[12];
    const float* wout = (const float*)d_in[13];
    const float* bout = (const float*)d_in[14];
    const float* trn  = (const float*)d_in[15];

    char* ws = (char*)d_ws;
    u16*   Xf     = (u16*)(ws);                       // 33,554,432 B
    u16*   Xb     = (u16*)(ws + 33554432);            // 33,554,432 B
    u16*   hfp    = (u16*)(ws + 67108864);            //  8,388,608 B
    u16*   hbp    = (u16*)(ws + 75497472);            //  8,388,608 B
    float* feats  = (float*)(ws + 83886080);          //    917,504 B
    float* chunkM = (float*)(ws + 84803584);          //    100,352 B

    hipMemsetAsync(d_out, 0, 4, stream);
    k_inproj2<<<512, 512, 0, stream>>>(sent, emb, wihf, bihf, bhhf,
                                       wihb, bihb, bhhb, Xf, Xb);
    k_lstm<<<8, 512, 0, stream>>>(h0, c0, whhf, whhb, Xf, Xb, hfp, hbp);
    k_feats<<<1024, 256, 0, stream>>>(hfp, hbp, wout, bout, feats);
    k_crf_chunk<<<512, 64, 0, stream>>>(feats, trn, chunkM);
    k_crf_final<<<64, 64, 0, stream>>>(chunkM, trn, tags, feats, (float*)d_out);
}

// Round 5
// 576.318 us; speedup vs baseline: 1.2791x; 1.0008x over previous
//
#include <hip/hip_runtime.h>

typedef unsigned int u32;
typedef unsigned short u16;
typedef __attribute__((ext_vector_type(8))) short short8;   // 8 bf16 (4 VGPRs)
typedef __attribute__((ext_vector_type(4))) float f32x4;

#define DEV __device__ __forceinline__
#define LOG2E 1.44269504089f

DEV u16 f2bf(float f) {
    u32 u = __float_as_uint(f);
    return (u16)((u + 0x7FFFu + ((u >> 16) & 1u)) >> 16);
}
DEV float bf2f(u16 h) { return __uint_as_float(((u32)h) << 16); }
DEV float frcp(float x) { return __builtin_amdgcn_rcpf(x); }
DEV float fexp2(float x) {
#if __has_builtin(__builtin_amdgcn_exp2f)
    return __builtin_amdgcn_exp2f(x);
#else
    return exp2f(x);
#endif
}
DEV u32 pack_bf16(float a, float b) {
#if __has_builtin(__builtin_amdgcn_cvt_pk_bf16_f32)
    auto v = __builtin_amdgcn_cvt_pk_bf16_f32(a, b);   // lo=a, hi=b
    u32 r; __builtin_memcpy(&r, &v, 4); return r;
#else
    return (u32)f2bf(a) | ((u32)f2bf(b) << 16);
#endif
}
// extract r-th bf16 (r constant under unroll) from packed uint2
DEV float xex(uint2 v, int r) {
    u32 u = (r & 2) ? v.y : v.x;
    return (r & 1) ? __uint_as_float(u & 0xFFFF0000u) : __uint_as_float(u << 16);
}

// ---------------------------------------------------------------------------
// K1 (R5): fused embedding gather + input projection, MFMA, both dirs.
// 256 blocks = 2 dirs x 128 chunks of 4 s-steps; each block covers ALL 64
// batch (4 N-tiles), so the 256KB weight matrix is fetched 256x (67 MB total,
// was 134 MB over 512 blocks) and amortized over 4x more MFMA per fetch.
// Emb staged 2 s-steps at a time (35 KB LDS).  X layout identical to R4.
// Output pre-scaled by log2e for k_lstm's raw v_exp.
// ---------------------------------------------------------------------------
__global__ __launch_bounds__(512) void k_inproj2(
    const int* __restrict__ sent, const float* __restrict__ emb,
    const float* __restrict__ wihf, const float* __restrict__ bihf, const float* __restrict__ bhhf,
    const float* __restrict__ wihb, const float* __restrict__ bihb, const float* __restrict__ bhhb,
    u16* __restrict__ Xf, u16* __restrict__ Xb)
{
    int blk = blockIdx.x;
    int d  = blk >> 7;
    int sc = blk & 127;                    // 4 s-steps per block
    const float* wih = d ? wihb : wihf;
    const float* bih = d ? bihb : bihf;
    const float* bhh = d ? bhhb : bhhf;
    u16* X = d ? Xb : Xf;
    int tid = threadIdx.x;
    int w = tid >> 6, lane = tid & 63;
    int rg = lane >> 4, cn = lane & 15;

    short8 afr[4][4];                      // A[m=lane&15][k=(lane>>4)*8+j]
    #pragma unroll
    for (int mi = 0; mi < 4; ++mi) {
        int gate = 16 * (w + 8 * mi) + cn;
        #pragma unroll
        for (int kt = 0; kt < 4; ++kt) {
            const float* p = wih + (size_t)gate * 128 + kt * 32 + rg * 8;
            float4 f0 = *(const float4*)p;
            float4 f1 = *(const float4*)(p + 4);
            union { short8 v; u32 u[4]; } sv;
            sv.u[0] = pack_bf16(f0.x, f0.y);
            sv.u[1] = pack_bf16(f0.z, f0.w);
            sv.u[2] = pack_bf16(f1.x, f1.y);
            sv.u[3] = pack_bf16(f1.z, f1.w);
            afr[mi][kt] = sv.v;
        }
    }
    float bs[4][4];
    #pragma unroll
    for (int mi = 0; mi < 4; ++mi)
        #pragma unroll
        for (int r = 0; r < 4; ++r) {
            int g = 16 * (w + 8 * mi) + 4 * rg + r;
            bs[mi][r] = bih[g] + bhh[g];
        }

    __shared__ u16 tile[2][64][136];       // 2 s-steps x 64 batch x 128 ch
    #pragma unroll
    for (int stage = 0; stage < 2; ++stage) {
        if (stage) __syncthreads();        // protect LDS reuse
        {
            int row = tid >> 2, q = tid & 3;   // 128 rows (2s x 64b), 32 ch each
            int sl = row >> 6, bb = row & 63;
            int tok = sent[(sc * 4 + stage * 2 + sl) * 64 + bb];
            const float* er = emb + (size_t)tok * 128 + q * 32;
            u16* dst = &tile[sl][bb][q * 32];
            #pragma unroll
            for (int u = 0; u < 4; ++u) {
                float4 a = *(const float4*)(er + u * 8);
                float4 c = *(const float4*)(er + u * 8 + 4);
                uint4 st;
                st.x = pack_bf16(a.x, a.y); st.y = pack_bf16(a.z, a.w);
                st.z = pack_bf16(c.x, c.y); st.w = pack_bf16(c.z, c.w);
                *(uint4*)(dst + u * 8) = st;
            }
        }
        __syncthreads();
        #pragma unroll
        for (int ss = 0; ss < 2; ++ss) {
            int s = sc * 4 + stage * 2 + ss;
            #pragma unroll
            for (int nt = 0; nt < 4; ++nt) {       // N-tile = batch group g4
                short8 bfr[4];
                #pragma unroll
                for (int kt = 0; kt < 4; ++kt)
                    bfr[kt] = *(const short8*)&tile[ss][nt * 16 + cn][kt * 32 + rg * 8];
                #pragma unroll
                for (int mi = 0; mi < 4; ++mi) {
                    f32x4 acc = {0.f, 0.f, 0.f, 0.f};
                    #pragma unroll
                    for (int kt = 0; kt < 4; ++kt)
                        acc = __builtin_amdgcn_mfma_f32_16x16x32_bf16(afr[mi][kt], bfr[kt], acc, 0, 0, 0);
                    size_t base = (((size_t)s * 4 + nt) * 32 + (w + 8 * mi)) * 256
                                + (size_t)rg * 64 + (size_t)cn * 4;
                    uint2 st;
                    st.x = pack_bf16((acc[0] + bs[mi][0]) * LOG2E, (acc[1] + bs[mi][1]) * LOG2E);
                    st.y = pack_bf16((acc[2] + bs[mi][2]) * LOG2E, (acc[3] + bs[mi][3]) * LOG2E);
                    *(uint2*)(X + base) = st;
                }
            }
        }
    }
}

// ---------------------------------------------------------------------------
// K2 (R5): bidirectional LSTM recurrence.  8 blocks = 2 dirs x 4 groups(16).
// R4 skeleton (2x unroll, static LDS ping-pong, acc-from-X, depth-2 in-place
// X reloads, LDS-only barrier) + R5: all in-loop global addressing is uniform
// scalar base + static lane offset (1 s_add per step instead of 8 v_add_co
// chains), tightened 16-VALU/5-exp/2-rcp cell with fma forms.
// ---------------------------------------------------------------------------
__global__ __launch_bounds__(512) void k_lstm(
    const float* __restrict__ h0, const float* __restrict__ c0,
    const float* __restrict__ whhf, const float* __restrict__ whhb,
    const u16* __restrict__ Xf, const u16* __restrict__ Xb,
    u16* __restrict__ hfo, u16* __restrict__ hbo)
{
    int d  = blockIdx.x >> 2, g4 = blockIdx.x & 3;
    const float* whh = d ? whhb : whhf;
    const u16*   X   = d ? Xb   : Xf;
    u16*         ho  = d ? hbo  : hfo;
    int w = threadIdx.x >> 6, lane = threadIdx.x & 63;
    int rg = lane >> 4, cn = lane & 15;

    short8 afr[4][4];                  // whh * log2e, A-frag layout
    #pragma unroll
    for (int mi = 0; mi < 4; ++mi) {
        int gate = 16 * (w + 8 * mi) + cn;
        #pragma unroll
        for (int kt = 0; kt < 4; ++kt) {
            const float* p = whh + (size_t)gate * 128 + kt * 32 + rg * 8;
            float4 f0 = *(const float4*)p;
            float4 f1 = *(const float4*)(p + 4);
            union { short8 v; u32 u[4]; } sv;
            sv.u[0] = pack_bf16(f0.x * LOG2E, f0.y * LOG2E);
            sv.u[1] = pack_bf16(f0.z * LOG2E, f0.w * LOG2E);
            sv.u[2] = pack_bf16(f1.x * LOG2E, f1.y * LOG2E);
            sv.u[3] = pack_bf16(f1.z * LOG2E, f1.w * LOG2E);
            afr[mi][kt] = sv.v;
        }
    }
    int b = g4 * 16 + cn;
    int chb = 16 * w + rg * 4;
    float cst[4];
    {
        float4 cv = *(const float4*)(c0 + ((size_t)d * 64 + b) * 128 + chb);
        cst[0]=cv.x; cst[1]=cv.y; cst[2]=cv.z; cst[3]=cv.w;
    }
    __shared__ u16 hbuf[2][16][136];
    {
        float4 hv = *(const float4*)(h0 + ((size_t)d * 64 + b) * 128 + chb);
        uint2 st0;
        st0.x = pack_bf16(hv.x, hv.y);
        st0.y = pack_bf16(hv.z, hv.w);
        *(uint2*)&hbuf[0][cn][chb] = st0;
    }
    __syncthreads();

    int s0 = d ? 511 : 0;
    const int sdB = d ? -65536 : 65536;     // X bytes per s-step
    const int hdB = d ? -16384 : 16384;     // h bytes per s-step

    // Static per-lane byte offsets; scalar (uniform) bases advance per step.
    int voffB[4];
    #pragma unroll
    for (int mi = 0; mi < 4; ++mi)
        voffB[mi] = 2 * ((w + 8 * mi) * 256 + rg * 64 + cn * 4);
    const char* xbase = (const char*)X + ((size_t)s0 * 32768 + (size_t)g4 * 8192) * 2;
    uint2 xA[4], xB[4];
    #pragma unroll
    for (int mi = 0; mi < 4; ++mi) {
        xA[mi] = *(const uint2*)(xbase + voffB[mi]);
        xB[mi] = *(const uint2*)(xbase + sdB + voffB[mi]);
    }
    const char* sxA = xbase + 2 * sdB;      // reload base for even steps (t+2)
    const char* sxB = xbase + 3 * sdB;      // reload base for odd steps
    int vhoff = 2 * (b * 128 + chb);
    char* hsp = (char*)ho + (size_t)s0 * 16384;

    // One recurrence substep: read hbuf[RB], write hbuf[WB]; consume XC (acc
    // init), then reload XC for t+2 from scalar base SX (advances 2 steps).
#define LSTM_STEP(RB, WB, XC, SX)                                            \
    do {                                                                     \
        short8 bfr[4];                                                       \
        _Pragma("unroll")                                                    \
        for (int kt = 0; kt < 4; ++kt)                                       \
            bfr[kt] = *(const short8*)&hbuf[RB][cn][kt * 32 + rg * 8];       \
        f32x4 z[4];                                                          \
        _Pragma("unroll")                                                    \
        for (int mi = 0; mi < 4; ++mi) {                                     \
            f32x4 acc;                                                       \
            acc[0] = xex(XC[mi], 0); acc[1] = xex(XC[mi], 1);                \
            acc[2] = xex(XC[mi], 2); acc[3] = xex(XC[mi], 3);                \
            _Pragma("unroll")                                                \
            for (int kt = 0; kt < 4; ++kt)                                   \
                acc = __builtin_amdgcn_mfma_f32_16x16x32_bf16(               \
                    afr[mi][kt], bfr[kt], acc, 0, 0, 0);                     \
            z[mi] = acc;                                                     \
            XC[mi] = *(const uint2*)(SX + voffB[mi]);                        \
        }                                                                    \
        SX += 2 * sdB;                                                       \
        float hnew[4];                                                       \
        _Pragma("unroll")                                                    \
        for (int r = 0; r < 4; ++r) {                                        \
            float zi = z[0][r], zf = z[1][r], zg = z[2][r], zo = z[3][r];    \
            float ei = fexp2(-zi);                                           \
            float ef = fexp2(-zf);                                           \
            float eo = fexp2(-zo);                                           \
            float eg = fexp2(fminf(zg + zg, 126.f));                         \
            float A = 1.f + ei, F = 1.f + ef, G = 1.f + eg, O = 1.f + eo;    \
            float AG = A * G;                                                \
            float num = fmaf(cst[r], AG, (eg - 1.f) * F);                    \
            float cc  = num * frcp(F * AG);                                  \
            cst[r] = cc;                                                     \
            float ec = fexp2(fminf(2.885390082f * cc, 126.f));               \
            hnew[r] = (ec - 1.f) * frcp(fmaf(O, ec, O));                     \
        }                                                                    \
        uint2 st;                                                            \
        st.x = pack_bf16(hnew[0], hnew[1]);                                  \
        st.y = pack_bf16(hnew[2], hnew[3]);                                  \
        *(uint2*)&hbuf[WB][cn][chb] = st;                                    \
        *(uint2*)(hsp + vhoff) = st;                                         \
        hsp += hdB;                                                          \
        asm volatile("s_waitcnt lgkmcnt(0)\n\ts_barrier" ::: "memory");      \
    } while (0)

    for (int it = 0; it < 256; ++it) {
        LSTM_STEP(0, 1, xA, sxA);
        LSTM_STEP(1, 0, xB, sxB);
    }
#undef LSTM_STEP
}

// ---------------------------------------------------------------------------
// K3: feats[s,b,t] = [hf|hb] . w_out[t] + b_out[t].   block handles 32 pos.
// ---------------------------------------------------------------------------
__global__ __launch_bounds__(256) void k_feats(
    const u16* __restrict__ hf, const u16* __restrict__ hb,
    const float* __restrict__ wout, const float* __restrict__ bout,
    float* __restrict__ feats)
{
    __shared__ u16 sf[32][136], sb[32][136];
    __shared__ float wo[7][260];
    __shared__ float bo[8];
    int tid = threadIdx.x;
    int pos0 = blockIdx.x * 32;
    {
        int r = tid >> 3, cc = (tid & 7) * 16;
        const uint4* pf = (const uint4*)(hf + (size_t)(pos0 + r) * 128 + cc);
        const uint4* pb = (const uint4*)(hb + (size_t)(pos0 + r) * 128 + cc);
        *(uint4*)&sf[r][cc]     = pf[0];
        *(uint4*)&sf[r][cc + 8] = pf[1];
        *(uint4*)&sb[r][cc]     = pb[0];
        *(uint4*)&sb[r][cc + 8] = pb[1];
    }
    for (int i = tid; i < 1792; i += 256) wo[i >> 8][i & 255] = wout[i];
    if (tid < 7) bo[tid] = bout[tid];
    __syncthreads();
    int pp = tid >> 3, tt = tid & 7;
    if (tt < 7) {
        float acc = bo[tt];
        #pragma unroll 4
        for (int ch = 0; ch < 128; ++ch)
            acc += bf2f(sf[pp][ch]) * wo[tt][ch]
                 + bf2f(sb[pp][ch]) * wo[tt][128 + ch];
        feats[(size_t)(pos0 + pp) * 7 + tt] = acc;
    }
}

// ---------------------------------------------------------------------------
// K4a: CRF chunk fold.  block=(b, chunk of 64 steps).
// ---------------------------------------------------------------------------
__global__ __launch_bounds__(64) void k_crf_chunk(
    const float* __restrict__ feats, const float* __restrict__ trans,
    float* __restrict__ chunkM)
{
    int b = blockIdx.x >> 3, c = blockIdx.x & 7;
    int lane = threadIdx.x;
    int i = lane >> 3, j = lane & 7;
    __shared__ float M[8][8];
    __shared__ float fl[64][8];
    int s0 = c * 64;
    for (int idx = lane; idx < 448; idx += 64) {
        int ss = idx / 7, jj = idx - ss * 7;
        fl[ss][jj] = feats[(size_t)((s0 + ss) * 64 + b) * 7 + jj];
    }
    float tc[7];
    #pragma unroll
    for (int k = 0; k < 7; ++k) tc[k] = (j < 7) ? trans[k * 7 + j] : 0.f;
    __syncthreads();
    M[i][j] = (i < 7 && j < 7) ? (trans[i * 7 + j] + fl[0][j]) : -1e30f;
    __syncthreads();
    for (int ss = 1; ss < 64; ++ss) {
        float4 m0 = *(const float4*)&M[i][0];
        float4 m1 = *(const float4*)&M[i][4];
        float v0 = m0.x + tc[0], v1 = m0.y + tc[1], v2 = m0.z + tc[2];
        float v3 = m0.w + tc[3], v4 = m1.x + tc[4], v5 = m1.y + tc[5];
        float v6 = m1.z + tc[6];
        float mx = fmaxf(fmaxf(fmaxf(v0, v1), fmaxf(v2, v3)),
                         fmaxf(fmaxf(v4, v5), v6));
        float sm = __expf(v0 - mx) + __expf(v1 - mx) + __expf(v2 - mx)
                 + __expf(v3 - mx) + __expf(v4 - mx) + __expf(v5 - mx)
                 + __expf(v6 - mx);
        float r = mx + __logf(sm) + fl[ss][j];
        __syncthreads();
        if (i < 7 && j < 7) M[i][j] = r;
        __syncthreads();
    }
    if (i < 7 && j < 7)
        chunkM[(size_t)(b * 8 + c) * 49 + i * 7 + j] = M[i][j];
}

// ---------------------------------------------------------------------------
// K4b: fold 8 chunk matrices + alpha0 + STOP row; gold score; atomicAdd.
// ---------------------------------------------------------------------------
__global__ __launch_bounds__(64) void k_crf_final(
    const float* __restrict__ chunkM, const float* __restrict__ trans,
    const int* __restrict__ tags, const float* __restrict__ feats,
    float* __restrict__ out)
{
    int b = blockIdx.x;
    int lane = threadIdx.x;
    __shared__ float P[8][49];
    __shared__ float Tl[49];
    __shared__ float av[2][8];
    __shared__ int   tg[512];
    for (int idx = lane; idx < 392; idx += 64)
        P[idx / 49][idx % 49] = chunkM[(size_t)b * 392 + idx];
    if (lane < 49) Tl[lane] = trans[lane];
    for (int idx = lane; idx < 512; idx += 64) tg[idx] = tags[(size_t)b * 512 + idx];
    if (lane < 8) av[0][lane] = (lane == 5) ? 0.f : -1e4f;
    __syncthreads();
    int cur = 0;
    for (int cch = 0; cch < 8; ++cch) {
        if (lane < 7) {
            float vv[7], mx = -1e30f;
            #pragma unroll
            for (int ii = 0; ii < 7; ++ii) {
                vv[ii] = av[cur][ii] + P[cch][ii * 7 + lane];
                mx = fmaxf(mx, vv[ii]);
            }
            float sm = 0.f;
            #pragma unroll
            for (int ii = 0; ii < 7; ++ii) sm += __expf(vv[ii] - mx);
            av[cur ^ 1][lane] = mx + __logf(sm);
        }
        __syncthreads();
        cur ^= 1;
    }
    float mx = -1e30f, uu[7];
    #pragma unroll
    for (int jj = 0; jj < 7; ++jj) {
        uu[jj] = av[cur][jj] + Tl[6 * 7 + jj];
        mx = fmaxf(mx, uu[jj]);
    }
    float sm = 0.f;
    #pragma unroll
    for (int jj = 0; jj < 7; ++jj) sm += __expf(uu[jj] - mx);
    float fwd = mx + __logf(sm);
    float acc = 0.f;
    for (int ss = lane; ss < 512; ss += 64) {
        int tn = tg[ss];
        int tp = (ss == 0) ? 5 : tg[ss - 1];
        acc += Tl[tn * 7 + tp] + feats[(size_t)(ss * 64 + b) * 7 + tn];
    }
    #pragma unroll
    for (int mk = 32; mk >= 1; mk >>= 1) acc += __shfl_xor(acc, mk, 64);
    if (lane == 0) {
        float gold = acc + Tl[6 * 7 + tg[511]];
        atomicAdd(out, (fwd - gold) * (1.0f / 64.0f));
    }
}

// ---------------------------------------------------------------------------
extern "C" void kernel_launch(void* const* d_in, const int* in_sizes, int n_in,
                              void* d_out, int out_size, void* d_ws, size_t ws_size,
                              hipStream_t stream) {
    const int*   sent = (const int*)d_in[0];
    const int*   tags = (const int*)d_in[1];
    const float* h0   = (const float*)d_in[2];
    const float* c0   = (const float*)d_in[3];
    const float* emb  = (const float*)d_in[4];
    const float* wihf = (const float*)d_in[5];
    const float* whhf = (const float*)d_in[6];
    const float* bihf = (const float*)d_in[7];
    const float* bhhf = (const float*)d_in[8];
    const float* wihb = (const float*)d_in[9];
    const float* whhb = (const float*)d_in[10];
    const float* bihb = (const float*)d_in[11];
    const float* bhhb = (const float*)d_in[12];
    const float* wout = (const float*)d_in[13];
    const float* bout = (const float*)d_in[14];
    const float* trn  = (const float*)d_in[15];

    char* ws = (char*)d_ws;
    u16*   Xf     = (u16*)(ws);                       // 33,554,432 B
    u16*   Xb     = (u16*)(ws + 33554432);            // 33,554,432 B
    u16*   hfp    = (u16*)(ws + 67108864);            //  8,388,608 B
    u16*   hbp    = (u16*)(ws + 75497472);            //  8,388,608 B
    float* feats  = (float*)(ws + 83886080);          //    917,504 B
    float* chunkM = (float*)(ws + 84803584);          //    100,352 B

    hipMemsetAsync(d_out, 0, 4, stream);
    k_inproj2<<<256, 512, 0, stream>>>(sent, emb, wihf, bihf, bhhf,
                                       wihb, bihb, bhhb, Xf, Xb);
    k_lstm<<<8, 512, 0, stream>>>(h0, c0, whhf, whhb, Xf, Xb, hfp, hbp);
    k_feats<<<1024, 256, 0, stream>>>(hfp, hbp, wout, bout, feats);
    k_crf_chunk<<<512, 64, 0, stream>>>(feats, trn, chunkM);
    k_crf_final<<<64, 64, 0, stream>>>(chunkM, trn, tags, feats, (float*)d_out);
}